// Round 13
// baseline (250.681 us; speedup 1.0000x reference)
//
#include <hip/hip_runtime.h>
#include <hip/hip_bf16.h>

typedef __attribute__((ext_vector_type(8))) short bf16x8;
typedef __attribute__((ext_vector_type(4))) float f32x4;
typedef __attribute__((ext_vector_type(4))) unsigned int u32x4;

#define HW (512 * 512)
#define TW 64
#define SLOTS 6                  // tile row slots: 4 read + 2 write, disjoint
#define PXG (SLOTS * 66)         // 396 pixels per ic-group
#define TILE_B (4 * PXG * 16)    // 25344: bf16 [g][pixel] MFMA tile
#define STAGE_SZ 18432           // f32 stage: 32ch x 2row x 288B (18 x 1KB units)
#define DUMMY (TILE_B + 3 * STAGE_SZ)   // 80640; +1KB dummy -> 81664 (1 block/CU)

#define SCHED() __builtin_amdgcn_sched_barrier(0)

__device__ __forceinline__ unsigned short f2bf(float f) {
    unsigned u = __builtin_bit_cast(unsigned, f);
    u += 0x7FFFu + ((u >> 16) & 1u);   // RNE
    return (unsigned short)(u >> 16);
}

__device__ __forceinline__ void gll16(const float* g, char* l) {
    __builtin_amdgcn_global_load_lds(
        (const __attribute__((address_space(1))) void*)g,
        (__attribute__((address_space(3))) void*)l, 16, 0, 0);
}

// stage rows {row0,row0+1} of all 32 ch into stage buffer: [ch:32][hh:2][72 f32].
// 20 x 1KB gll instrs, uniformly 5 per wave (units 18,19 idempotently dup unit 17)
// -> per-wave vmcnt arithmetic exact.
__device__ __forceinline__ void issue_stage(const float* __restrict__ xb, int row0,
                                            int w0, char* smem, int sidx, int wvu) {
    const int lane = (int)threadIdx.x & 63;
    char* base = smem + TILE_B + sidx * STAGE_SZ;
    #pragma unroll
    for (int i = 0; i < 5; ++i) {
        int j = wvu * 5 + i;
        int ob = (j < 18 ? j : 17) * 1024;
        int o  = ob + lane * 16;
        int ch = o / 576;
        int rem = o - ch * 576;
        int hh = rem / 288;
        int wl = (rem - hh * 288) >> 2;               // 0..71
        int row = row0 + hh; row = row < 511 ? row : 511;
        int cb = w0 - 4 + wl;
        cb = cb < 0 ? 0 : (cb > 508 ? 508 : cb);      // stays 16B-aligned
        gll16(xb + (size_t)ch * HW + row * 512 + cb, base + ob);
    }
}

template<int W, bool TRANS, bool GLL, bool BAR>
__device__ __forceinline__ void body(char* smem, const float* __restrict__ xb,
                                     float* __restrict__ ob, bf16x8 (&wf)[9][2],
                                     int srb, int sc, int si, int rowbase, int w0,
                                     int wv, int wvu, int col16, int g4) {
    // ---- issue loads for t+2 (ring buffer; in flight across TWO iterations) ----
    if (GLL) issue_stage(xb, rowbase + 7, w0, smem, si, wvu);

    // ---- transpose+convert stage[sc] (x rows rowbase+3,+4) -> tile slots srb+4,srb+5 ----
    if (TRANS) {
        const char* sb = smem + TILE_B + sc * STAGE_SZ;
        const int rowA = rowbase + 3;
        #pragma unroll
        for (int k = 0; k < 3; ++k) {
            if (k == 2 && threadIdx.x >= 32) continue;
            int u = (k < 2) ? (int)threadIdx.x + k * 256 : 512 + (int)threadIdx.x;
            int g = u / 136, r = u - g * 136, sl = r / 68, ww = r - sl * 68;
            float v[8];
            int ba = g * 8 * 576 + sl * 288 + (ww + 3) * 4;
            #pragma unroll
            for (int j = 0; j < 8; ++j) v[j] = *(const float*)(sb + ba + j * 576);
            bool ok = (ww < 66) & ((unsigned)(w0 + ww - 1) < 512u) & (rowA + sl < 512);
            #pragma unroll
            for (int j = 0; j < 8; ++j) v[j] = ok ? v[j] : 0.f;
            unsigned q0 = (unsigned)f2bf(v[0]) | ((unsigned)f2bf(v[1]) << 16);
            unsigned q1 = (unsigned)f2bf(v[2]) | ((unsigned)f2bf(v[3]) << 16);
            unsigned q2 = (unsigned)f2bf(v[4]) | ((unsigned)f2bf(v[5]) << 16);
            unsigned q3 = (unsigned)f2bf(v[6]) | ((unsigned)f2bf(v[7]) << 16);
            int slot = srb + 4 + sl; if (slot >= SLOTS) slot -= SLOTS;
            int byte = (ww < 66) ? (g * PXG + slot * 66 + ww) * 16
                                 : (DUMMY + ((int)threadIdx.x & 63) * 16);
            u32x4 q = { q0, q1, q2, q3 };
            *(u32x4*)(smem + byte) = q;
        }
    }

    // ---- compute: output rows rowbase+(wv&1), w-half (wv>>1) ----
    f32x4 acc[2][2];
    {
        f32x4 z = {0.f, 0.f, 0.f, 0.f};
        acc[0][0] = z; acc[0][1] = z; acc[1][0] = z; acc[1][1] = z;
    }
    int rs[3];
    #pragma unroll
    for (int dh = 0; dh < 3; ++dh) {
        int s = srb + (wv & 1) + dh; if (s >= SLOTS) s -= SLOTS;
        rs[dh] = s * 66;
    }
    const int wcb = (wv >> 1) * 32;
    const char* xg = smem + g4 * (PXG * 16);
    #pragma unroll
    for (int dh = 0; dh < 3; ++dh) {
        #pragma unroll
        for (int dw = 0; dw < 3; ++dw) {
            const int tap = dh * 3 + dw;
            #pragma unroll
            for (int m = 0; m < 2; ++m) {
                bf16x8 a = *(const bf16x8*)(xg + (rs[dh] + wcb + m * 16 + col16 + dw) * 16);
                acc[m][0] = __builtin_amdgcn_mfma_f32_16x16x32_bf16(a, wf[tap][0], acc[m][0], 0, 0, 0);
                acc[m][1] = __builtin_amdgcn_mfma_f32_16x16x32_bf16(a, wf[tap][1], acc[m][1], 0, 0, 0);
            }
        }
    }
    {
        float* orow = ob + (size_t)(rowbase + (wv & 1)) * 512 + w0 + wcb;
        #pragma unroll
        for (int m = 0; m < 2; ++m)
            #pragma unroll
            for (int n = 0; n < 2; ++n)
                *(f32x4*)(orow + (size_t)(n * 16 + col16) * HW + m * 16 + g4 * 4) = acc[m][n];
    }

    if (BAR) {
        // W=9: retire gll(t-1)+older; keep gll(t) [5] + this iter's stores [4] in flight
        if constexpr (W == 9) asm volatile("s_waitcnt vmcnt(9)" ::: "memory");
        else                  asm volatile("s_waitcnt vmcnt(4)" ::: "memory");
        SCHED();
        asm volatile("s_waitcnt lgkmcnt(0)" ::: "memory");
        SCHED();
        __builtin_amdgcn_s_barrier();
        SCHED();
    }
}

__global__ __launch_bounds__(256, 2)
void conv3x3_mfma(const float* __restrict__ x,
                  const float* __restrict__ wk,
                  float* __restrict__ out) {
    __shared__ __align__(16) char smem[DUMMY + 1024];   // 81664 B -> 1 block/CU

    const int tid   = (int)threadIdx.x;
    const int lane  = tid & 63;
    const int wv    = tid >> 6;
    const int wvu   = __builtin_amdgcn_readfirstlane(wv);
    const int col16 = lane & 15;
    const int g4    = lane >> 4;

    // ---- XCD-coherent remap (proven R12): 8 w-neighbor blocks share an XCD ----
    const int wg  = (int)blockIdx.x;
    const int xcd = wg & 7;
    const int i   = wg >> 3;
    const int xq  = i & 7;
    const int pg  = xcd + 8 * (i >> 3);
    const int yq  = pg & 7;
    const int zq  = pg >> 3;

    const int w0    = xq * TW;
    const int hbase = yq * 64;
    const int b     = zq;

    const float* xb = x + (size_t)b * 32 * HW;
    float* ob = out + (size_t)b * 32 * HW;

    // ---- prologue 1: weights f32 -> stage region scratch ----
    {
        float* ws = (float*)(smem + TILE_B);   // 36992 B <= 3*18432
        for (int i2 = tid; i2 < 9216; i2 += 256) {
            int oc = i2 / 288;
            ws[oc * 289 + (i2 - oc * 288)] = wk[i2];
        }
    }
    // ---- prologue 2: x rows hbase-1..hbase+2 -> regs (1056 units) ----
    float svp[5][8];
    #pragma unroll
    for (int k = 0; k < 5; ++k) {
        if (k == 4 && tid >= 32) continue;
        int u = (k < 4) ? tid + k * 256 : 1024 + tid;
        int g = u / 264, p = u - g * 264, hh = p / 66, ww = p - hh * 66;
        int row = hbase + hh - 1, cl = w0 + ww - 1;
        bool ok = ((unsigned)row < 512u) & ((unsigned)cl < 512u);
        int rowc = row < 0 ? 0 : (row > 511 ? 511 : row);
        int clc  = cl  < 0 ? 0 : (cl  > 511 ? 511 : cl);
        const float* src = xb + (size_t)(g * 8) * HW + rowc * 512 + clc;
        #pragma unroll
        for (int j = 0; j < 8; ++j) { float v = src[(size_t)j * HW]; svp[k][j] = ok ? v : 0.f; }
    }
    __syncthreads();   // weights scratch visible

    // ---- prologue 3: gather weight fragments to registers ----
    bf16x8 wf[9][2];
    {
        const float* ws = (const float*)(smem + TILE_B);
        #pragma unroll
        for (int tap = 0; tap < 9; ++tap) {
            #pragma unroll
            for (int n = 0; n < 2; ++n) {
                bf16x8 f;
                #pragma unroll
                for (int j = 0; j < 8; ++j)
                    f[j] = (short)f2bf(ws[(n * 16 + col16) * 289 + (g4 * 8 + j) * 9 + tap]);
                wf[tap][n] = f;
            }
        }
    }
    __syncthreads();   // scratch free before gll writes stage

    // ---- prologue 4: write tile slots 0..3; issue stage 0 (rows 3,4) + 1 (rows 5,6) ----
    #pragma unroll
    for (int k = 0; k < 5; ++k) {
        if (k == 4 && tid >= 32) continue;
        int u = (k < 4) ? tid + k * 256 : 1024 + tid;
        int g = u / 264, p = u - g * 264;       // p = slot*66+ww directly
        unsigned q0 = (unsigned)f2bf(svp[k][0]) | ((unsigned)f2bf(svp[k][1]) << 16);
        unsigned q1 = (unsigned)f2bf(svp[k][2]) | ((unsigned)f2bf(svp[k][3]) << 16);
        unsigned q2 = (unsigned)f2bf(svp[k][4]) | ((unsigned)f2bf(svp[k][5]) << 16);
        unsigned q3 = (unsigned)f2bf(svp[k][6]) | ((unsigned)f2bf(svp[k][7]) << 16);
        u32x4 q = { q0, q1, q2, q3 };
        *(u32x4*)(smem + (g * PXG + p) * 16) = q;
    }
    SCHED();
    issue_stage(xb, hbase + 3, w0, smem, 0, wvu);   // batch for t=0
    issue_stage(xb, hbase + 5, w0, smem, 1, wvu);   // batch for t=1
    SCHED();
    asm volatile("s_waitcnt vmcnt(5)" ::: "memory");  // stage 0 landed; stage 1 in flight
    SCHED();
    asm volatile("s_waitcnt lgkmcnt(0)" ::: "memory");
    SCHED();
    __builtin_amdgcn_s_barrier();
    SCHED();

    // iter t: trans stage[t%3], issue gll(t+2)->stage[(t+2)%3], compute rows 2t,2t+1
    int srb = 0;
    #pragma unroll 1
    for (int t = 0; t < 29; ++t) {
        int sc = t % 3;
        int si = sc + 2; if (si >= 3) si -= 3;
        body<9, 1, 1, 1>(smem, xb, ob, wf, srb, sc, si, hbase + 2 * t, w0, wv, wvu, col16, g4);
        srb += 2; if (srb >= SLOTS) srb -= SLOTS;
    }
    // t = 29: trans stage[2]; no issue; drain remaining gll (keep stores)
    body<4, 1, 0, 1>(smem, xb, ob, wf, srb, 2, 0, hbase + 58, w0, wv, wvu, col16, g4);
    srb += 2; if (srb >= SLOTS) srb -= SLOTS;
    // t = 30: trans stage[0] (rows 63,64); no issue
    body<4, 1, 0, 1>(smem, xb, ob, wf, srb, 0, 0, hbase + 60, w0, wv, wvu, col16, g4);
    srb += 2; if (srb >= SLOTS) srb -= SLOTS;
    // t = 31: compute only
    body<4, 0, 0, 0>(smem, xb, ob, wf, srb, 0, 0, hbase + 62, w0, wv, wvu, col16, g4);
}

extern "C" void kernel_launch(void* const* d_in, const int* in_sizes, int n_in,
                              void* d_out, int out_size, void* d_ws, size_t ws_size,
                              hipStream_t stream) {
    const float* x  = (const float*)d_in[0];
    const float* wk = (const float*)d_in[1];
    float* out = (float*)d_out;
    conv3x3_mfma<<<dim3(1024, 1, 1), 256, 0, stream>>>(x, wk, out);
}